// Round 7
// baseline (305.066 us; speedup 1.0000x reference)
//
#include <hip/hip_runtime.h>
#include <math.h>

namespace {
constexpr int   QUALITY = 8;
constexpr int   NPART   = 18000 * QUALITY * QUALITY;  // 1,152,000
constexpr int   NG      = 128 * QUALITY;              // 1024
constexpr int   NCELL   = NG * NG;                    // 1,048,576
constexpr int   CTILE   = 16;                         // gather tile side (cells)
constexpr int   NBT     = NG / CTILE;                 // 64 tiles per side
constexpr float DX      = 1.0f / (float)NG;
constexpr float INV_DX  = (float)NG;
constexpr float DT      = (float)(1e-4 / (double)QUALITY);
constexpr float P_VOL   = (float)((0.5 / (double)NG) * (0.5 / (double)NG));
constexpr float P_MASS  = P_VOL;  // density 1.0
constexpr float MU0     = (float)(5000.0 / (2.0 * (1.0 + 0.2)));
constexpr float LAM0    = (float)(5000.0 * 0.2 / ((1.0 + 0.2) * (1.0 - 0.4)));
constexpr float STRESS_SCALE = (float)(-(1e-4 / 8.0) * ((0.5 / 1024.0) * (0.5 / 1024.0)) * 4.0 * 1024.0 * 1024.0);
constexpr float GRAV_SCALE   = (float)((1e-4 / 8.0) * 30.0);
constexpr float ATTR_SCALE   = (float)((1e-4 / 8.0) * 100.0);

// base cell of a particle, clamped so base+2 is in range (matches ref for this data)
__device__ __forceinline__ int2 base_of(float xx, float xy) {
    int bx = (int)floorf(xx * INV_DX - 0.5f);
    int by = (int)floorf(xy * INV_DX - 0.5f);
    bx = min(max(bx, 0), NG - 3);
    by = min(max(by, 0), NG - 3);
    return make_int2(bx, by);
}
}

// ---- K1: per-cell histogram ----
__global__ __launch_bounds__(256)
void count_kernel(const float* __restrict__ x, int* __restrict__ cnt) {
    int p = blockIdx.x * blockDim.x + threadIdx.x;
    if (p >= NPART) return;
    const float2 xv = ((const float2*)x)[p];
    int2 b = base_of(xv.x, xv.y);
    atomicAdd(&cnt[b.x * NG + b.y], 1);
}

// ---- K2a: per-block (1024 cells) sums ----
__global__ __launch_bounds__(256)
void blocksum_kernel(const int* __restrict__ cnt, int* __restrict__ bsum) {
    __shared__ int sh[256];
    int t = threadIdx.x;
    int4 c = ((const int4*)cnt)[blockIdx.x * 256 + t];
    sh[t] = c.x + c.y + c.z + c.w;
    __syncthreads();
    for (int s = 128; s > 0; s >>= 1) {
        if (t < s) sh[t] += sh[t + s];
        __syncthreads();
    }
    if (t == 0) bsum[blockIdx.x] = sh[0];
}

// ---- K2b: exclusive scan of the 1024 block sums ----
__global__ __launch_bounds__(1024)
void scanb_kernel(const int* __restrict__ bsum, int* __restrict__ boff,
                  int* __restrict__ cell_start) {
    __shared__ int s[1024];
    int t = threadIdx.x;
    int v = bsum[t];
    s[t] = v;
    __syncthreads();
    for (int off = 1; off < 1024; off <<= 1) {
        int add = (t >= off) ? s[t - off] : 0;
        __syncthreads();
        s[t] += add;
        __syncthreads();
    }
    boff[t] = s[t] - v;
    if (t == 1023) cell_start[NCELL] = s[t];
}

// ---- K2c: per-block scan of 1024 counts + block offset -> cell_start, cursor ----
__global__ __launch_bounds__(256)
void scanc_kernel(const int* __restrict__ cnt, const int* __restrict__ boff,
                  int* __restrict__ cell_start, int* __restrict__ cursor) {
    __shared__ int tsum[256];
    int t = threadIdx.x;
    int gbase4 = blockIdx.x * 256 + t;
    int4 c = ((const int4*)cnt)[gbase4];
    int s1 = c.x, s2 = s1 + c.y, s3 = s2 + c.z, tot = s3 + c.w;
    tsum[t] = tot;
    __syncthreads();
    for (int off = 1; off < 256; off <<= 1) {
        int add = (t >= off) ? tsum[t - off] : 0;
        __syncthreads();
        tsum[t] += add;
        __syncthreads();
    }
    int excl = tsum[t] - tot;
    int g = boff[blockIdx.x] + excl;
    int4 outv = make_int4(g, g + s1, g + s2, g + s3);
    ((int4*)cell_start)[gbase4] = outv;
    ((int4*)cursor)[gbase4] = outv;
}

// ---- K3: per-particle physics, ALL coalesced; only a 4B order scatter ----
__global__ __launch_bounds__(256)
void compute_scatter_kernel(const float* __restrict__ x, const float* __restrict__ v,
                            const float* __restrict__ Cin, const float* __restrict__ Fin,
                            const float* __restrict__ Jpin, const int* __restrict__ mat,
                            int* __restrict__ cursor, int* __restrict__ order,
                            float4* __restrict__ pay,
                            float* __restrict__ outF, float* __restrict__ outJp)
{
    int p = blockIdx.x * blockDim.x + threadIdx.x;
    if (p >= NPART) return;

    const float2 xv = ((const float2*)x)[p];
    const float2 vv = ((const float2*)v)[p];
    const float4 Cv = ((const float4*)Cin)[p];
    const float4 Fv = ((const float4*)Fin)[p];
    float xx = xv.x, xy = xv.y;
    float C00 = Cv.x, C01 = Cv.y, C10 = Cv.z, C11 = Cv.w;
    float F00 = Fv.x, F01 = Fv.y, F10 = Fv.z, F11 = Fv.w;

    // F = (I + DT*C) @ F
    float A00 = 1.0f + DT * C00, A01 = DT * C01, A10 = DT * C10, A11 = 1.0f + DT * C11;
    float G00 = A00 * F00 + A01 * F10;
    float G01 = A00 * F01 + A01 * F11;
    float G10 = A10 * F00 + A11 * F10;
    float G11 = A10 * F01 + A11 * F11;

    int m = mat[p];
    float Jp = Jpin[p];
    float h = fminf(fmaxf(expf(10.0f * (1.0f - Jp)), 0.1f), 5.0f);
    if (m == 1) h = 0.3f;
    float mu = (m == 0) ? 0.0f : MU0 * h;
    float la = LAM0 * h;

    // closed-form 2x2 SVD
    float Ee = 0.5f * (G00 + G11);
    float Hh = 0.5f * (G10 - G01);
    float Ff = 0.5f * (G00 - G11);
    float Gg = 0.5f * (G10 + G01);
    float Qq = sqrtf(Ee * Ee + Hh * Hh);
    float Rr = sqrtf(Ff * Ff + Gg * Gg);
    float s0 = Qq + Rr, s1 = Qq - Rr;
    float b1 = atan2f(Gg, Ff);
    float b2 = atan2f(Hh, Ee);
    float phi = 0.5f * (b1 + b2), th = 0.5f * (b1 - b2);
    float sphi, cphi, sth, cth;
    sincosf(phi, &sphi, &cphi);
    sincosf(th, &sth, &cth);

    float ns0 = s0, ns1 = s1;
    if (m == 2) {
        ns0 = fminf(fmaxf(s0, 1.0f - 2.5e-2f), 1.0f + 4.5e-3f);
        ns1 = fminf(fmaxf(s1, 1.0f - 2.5e-2f), 1.0f + 4.5e-3f);
        Jp = Jp * (s0 / ns0) * (s1 / ns1);
    }
    float J = ns0 * ns1;

    float FF00, FF01, FF10, FF11;
    if (m == 0) {
        float sj = sqrtf(J);
        FF00 = sj; FF01 = 0.0f; FF10 = 0.0f; FF11 = sj;
    } else if (m == 2) {
        FF00 = ns0 * cphi * cth + ns1 * sphi * sth;
        FF01 = ns0 * cphi * sth - ns1 * sphi * cth;
        FF10 = ns0 * sphi * cth - ns1 * cphi * sth;
        FF11 = ns0 * sphi * sth + ns1 * cphi * cth;
    } else {
        FF00 = G00; FF01 = G01; FF10 = G10; FF11 = G11;
    }

    // R = U V^T = rot(phi - th)
    float cr = cphi * cth + sphi * sth;
    float sr = sphi * cth - cphi * sth;

    float D00 = FF00 - cr,  D01 = FF01 + sr;
    float D10 = FF10 - sr,  D11 = FF11 - cr;
    float S00 = D00 * FF00 + D01 * FF01;
    float S01 = D00 * FF10 + D01 * FF11;
    float S10 = D10 * FF00 + D11 * FF01;
    float S11 = D10 * FF10 + D11 * FF11;
    float lj = la * J * (J - 1.0f);
    S00 = 2.0f * mu * S00 + lj;
    S01 = 2.0f * mu * S01;
    S10 = 2.0f * mu * S10;
    S11 = 2.0f * mu * S11 + lj;
    float a00 = STRESS_SCALE * S00 + P_MASS * C00;
    float a01 = STRESS_SCALE * S01 + P_MASS * C01;
    float a10 = STRESS_SCALE * S10 + P_MASS * C10;
    float a11 = STRESS_SCALE * S11 + P_MASS * C11;

    ((float4*)outF)[p] = make_float4(FF00, FF01, FF10, FF11);
    outJp[p] = Jp;

    // payload in PARTICLE order (coalesced); only the 4B index is scattered
    pay[2*p+0] = make_float4(xx, xy, P_MASS * vv.x, P_MASS * vv.y);
    pay[2*p+1] = make_float4(a00, a01, a10, a11);

    int2 b = base_of(xx, xy);
    int pos = atomicAdd(&cursor[b.x * NG + b.y], 1);
    order[pos] = p;
}

// ---- K4: atomic-free P2G gather (indirect payload reads), fused grid update ----
__global__ __launch_bounds__(256)
void p2g_gather_grid_kernel(const float4* __restrict__ pay,
                            const int* __restrict__ cell_start,
                            const int* __restrict__ order,
                            const float* __restrict__ grav,
                            const float* __restrict__ astr,
                            const float* __restrict__ apos,
                            float* __restrict__ gv)
{
    int tile = blockIdx.x;                 // 0..4095
    int trow = threadIdx.x / CTILE;        // 0..15
    int tcol = threadIdx.x % CTILE;
    int cx = (tile / NBT) * CTILE + trow;  // this thread's cell
    int cy = (tile % NBT) * CTILE + tcol;

    float svx = 0.0f, svy = 0.0f, sm = 0.0f;
    int c0 = max(cy - 2, 0);

    #pragma unroll
    for (int d = 0; d < 3; ++d) {
        int gxp = cx - 2 + d;              // particle base row; i = 2-d
        if (gxp < 0 || gxp > NG - 1) continue;
        int row = gxp * NG;
        int s = cell_start[row + c0];
        int e = cell_start[row + cy + 1];
        const float io = (float)(2 - d);
        for (int t = s; t < e; ++t) {
            int idx = order[t];
            float4 p0 = pay[2*idx+0];
            float4 p1 = pay[2*idx+1];
            float fx = p0.x * INV_DX;
            float bxf = floorf(fx - 0.5f);
            float fxx = fx - bxf;
            float fy = p0.y * INV_DX;
            float byf = floorf(fy - 0.5f);
            float fxy = fy - byf;
            int j = cy - (int)byf;
            if (j < 0 || j > 2) continue;  // defensive (empty in practice)
            float wx;
            if (d == 0)      wx = 0.5f * (fxx - 0.5f) * (fxx - 0.5f);        // i=2
            else if (d == 1) wx = 0.75f - (fxx - 1.0f) * (fxx - 1.0f);       // i=1
            else             wx = 0.5f * (1.5f - fxx) * (1.5f - fxx);        // i=0
            float w0 = 0.5f * (1.5f - fxy) * (1.5f - fxy);
            float w1 = 0.75f - (fxy - 1.0f) * (fxy - 1.0f);
            float w2 = 0.5f * (fxy - 0.5f) * (fxy - 0.5f);
            float wy = (j == 0) ? w0 : ((j == 1) ? w1 : w2);
            float wgt = wx * wy;
            float dpx = (io - fxx) * DX;
            float dpy = ((float)j - fxy) * DX;
            svx += wgt * (p0.z + p1.x * dpx + p1.y * dpy);
            svy += wgt * (p0.w + p1.z * dpx + p1.w * dpy);
            sm  += wgt * P_MASS;
        }
    }

    // fused grid update
    float vx = 0.0f, vy = 0.0f;
    if (sm > 0.0f) {
        vx = svx / sm + GRAV_SCALE * grav[0];
        vy = svy / sm + GRAV_SCALE * grav[1];
        float dxp = apos[0] - DX * (float)cx;
        float dyp = apos[1] - DX * (float)cy;
        float nrm = sqrtf(dxp * dxp + dyp * dyp);
        float k = astr[0] * ATTR_SCALE / (0.01f + nrm);
        vx += dxp * k;
        vy += dyp * k;
        if (cx < 3 && vx < 0.0f) vx = 0.0f;
        if (cx > NG - 3 && vx > 0.0f) vx = 0.0f;
        if (cy < 3 && vy < 0.0f) vy = 0.0f;
        if (cy > NG - 3 && vy > 0.0f) vy = 0.0f;
    }
    ((float2*)gv)[cx * NG + cy] = make_float2(vx, vy);
}

// ---- K5: G2P ----
__global__ __launch_bounds__(256)
void g2p_kernel(const float* __restrict__ x, const float* __restrict__ gv,
                float* __restrict__ outX, float* __restrict__ outV,
                float* __restrict__ outC)
{
    int p = blockIdx.x * blockDim.x + threadIdx.x;
    if (p >= NPART) return;

    const float2 xv = ((const float2*)x)[p];
    float xx = xv.x, xy = xv.y;
    float bxf = floorf(xx * INV_DX - 0.5f);
    float byf = floorf(xy * INV_DX - 0.5f);
    int bx = (int)bxf, by = (int)byf;
    float fxx = xx * INV_DX - bxf;
    float fxy = xy * INV_DX - byf;

    float wxs[3], wys[3];
    wxs[0] = 0.5f * (1.5f - fxx) * (1.5f - fxx);
    wxs[1] = 0.75f - (fxx - 1.0f) * (fxx - 1.0f);
    wxs[2] = 0.5f * (fxx - 0.5f) * (fxx - 0.5f);
    wys[0] = 0.5f * (1.5f - fxy) * (1.5f - fxy);
    wys[1] = 0.75f - (fxy - 1.0f) * (fxy - 1.0f);
    wys[2] = 0.5f * (fxy - 0.5f) * (fxy - 0.5f);

    float nvx = 0.0f, nvy = 0.0f;
    float c00 = 0.0f, c01 = 0.0f, c10 = 0.0f, c11 = 0.0f;

    #pragma unroll
    for (int i = 0; i < 3; ++i) {
        int gi = min(max(bx + i, 0), NG - 1);
        float dpx = (float)i - fxx;
        #pragma unroll
        for (int j = 0; j < 3; ++j) {
            int gj = min(max(by + j, 0), NG - 1);
            float dpy = (float)j - fxy;
            int idx = gi * NG + gj;
            float wgt = wxs[i] * wys[j];
            float2 g = ((const float2*)gv)[idx];
            nvx += wgt * g.x;
            nvy += wgt * g.y;
            c00 += wgt * g.x * dpx;
            c01 += wgt * g.x * dpy;
            c10 += wgt * g.y * dpx;
            c11 += wgt * g.y * dpy;
        }
    }
    float cs = 4.0f * INV_DX;
    ((float2*)outV)[p] = make_float2(nvx, nvy);
    ((float2*)outX)[p] = make_float2(xx + DT * nvx, xy + DT * nvy);
    ((float4*)outC)[p] = make_float4(cs * c00, cs * c01, cs * c10, cs * c11);
}

extern "C" void kernel_launch(void* const* d_in, const int* in_sizes, int n_in,
                              void* d_out, int out_size, void* d_ws, size_t ws_size,
                              hipStream_t stream)
{
    const float* x    = (const float*)d_in[0];
    const float* v    = (const float*)d_in[1];
    const float* C    = (const float*)d_in[2];
    const float* F    = (const float*)d_in[3];
    const float* Jp   = (const float*)d_in[4];
    const float* grav = (const float*)d_in[5];
    const float* astr = (const float*)d_in[6];
    const float* apos = (const float*)d_in[7];
    const int*   mat  = (const int*)d_in[8];

    float* out   = (float*)d_out;
    float* outX  = out;
    float* outV  = out + 2 * NPART;
    float* outC  = out + 4 * NPART;
    float* outF  = out + 8 * NPART;
    float* outJp = out + 12 * NPART;

    // workspace layout (4B units). gv aliases cnt+cursor (disjoint lifetimes):
    //   [0, NCELL)            : cnt    (K1..K2c)  | gv low half  (K4..K5)
    //   [NCELL, 2*NCELL)      : cursor (K2c..K3)  | gv high half (K4..K5)
    //   [2*NCELL, 3*NCELL+1]  : cell_start
    //   then bsum[1024], boff[1024], order[NPART], pad, pay[2*NPART] float4
    int*   ws_i      = (int*)d_ws;
    int*   cnt       = ws_i;
    int*   cursor    = ws_i + NCELL;
    float* gv        = (float*)d_ws;              // 2*NCELL floats, aliases cnt+cursor
    int*   cell_start= ws_i + 2 * NCELL;          // NCELL+1
    int*   bsum      = cell_start + NCELL + 1;    // 1024
    int*   boff      = bsum + 1024;               // 1024
    int*   order     = boff + 1024;               // NPART
    size_t pay_off   = (size_t)(3 * NCELL + 3 * 1024 + NPART + 16);
    pay_off = (pay_off + 3) & ~(size_t)3;         // 16B-align (float4 units)
    float4* pay      = (float4*)(ws_i + pay_off); // 2*NPART float4

    const int TB = 256;
    hipMemsetAsync(cnt, 0, (size_t)NCELL * sizeof(int), stream);
    count_kernel   <<<(NPART + TB - 1) / TB, TB, 0, stream>>>(x, cnt);
    blocksum_kernel<<<NCELL / 1024, TB, 0, stream>>>(cnt, bsum);
    scanb_kernel   <<<1, 1024, 0, stream>>>(bsum, boff, cell_start);
    scanc_kernel   <<<NCELL / 1024, TB, 0, stream>>>(cnt, boff, cell_start, cursor);
    compute_scatter_kernel<<<(NPART + TB - 1) / TB, TB, 0, stream>>>(
        x, v, C, F, Jp, mat, cursor, order, pay, outF, outJp);
    p2g_gather_grid_kernel<<<NBT * NBT, TB, 0, stream>>>(
        pay, cell_start, order, grav, astr, apos, gv);
    g2p_kernel     <<<(NPART + TB - 1) / TB, TB, 0, stream>>>(x, gv, outX, outV, outC);
}

// Round 8
// 251.923 us; speedup vs baseline: 1.2109x; 1.2109x over previous
//
#include <hip/hip_runtime.h>
#include <math.h>

namespace {
constexpr int   QUALITY = 8;
constexpr int   NPART   = 18000 * QUALITY * QUALITY;  // 1,152,000
constexpr int   NG      = 128 * QUALITY;              // 1024
constexpr int   NCELL   = NG * NG;                    // 1,048,576
constexpr int   CTILE   = 16;                         // gather tile side (cells)
constexpr int   NBT     = NG / CTILE;                 // 64 tiles per side
constexpr float DX      = 1.0f / (float)NG;
constexpr float INV_DX  = (float)NG;
constexpr float DT      = (float)(1e-4 / (double)QUALITY);
constexpr float P_VOL   = (float)((0.5 / (double)NG) * (0.5 / (double)NG));
constexpr float P_MASS  = P_VOL;  // density 1.0
constexpr float MU0     = (float)(5000.0 / (2.0 * (1.0 + 0.2)));
constexpr float LAM0    = (float)(5000.0 * 0.2 / ((1.0 + 0.2) * (1.0 - 0.4)));
constexpr float STRESS_SCALE = (float)(-(1e-4 / 8.0) * ((0.5 / 1024.0) * (0.5 / 1024.0)) * 4.0 * 1024.0 * 1024.0);
constexpr float GRAV_SCALE   = (float)((1e-4 / 8.0) * 30.0);
constexpr float ATTR_SCALE   = (float)((1e-4 / 8.0) * 100.0);

// base cell of a particle, clamped so base+2 is in range (matches ref for this data)
__device__ __forceinline__ int2 base_of(float xx, float xy) {
    int bx = (int)floorf(xx * INV_DX - 0.5f);
    int by = (int)floorf(xy * INV_DX - 0.5f);
    bx = min(max(bx, 0), NG - 3);
    by = min(max(by, 0), NG - 3);
    return make_int2(bx, by);
}
}

// ---- K1: per-cell histogram ----
__global__ __launch_bounds__(256)
void count_kernel(const float* __restrict__ x, int* __restrict__ cnt) {
    int p = blockIdx.x * blockDim.x + threadIdx.x;
    if (p >= NPART) return;
    const float2 xv = ((const float2*)x)[p];
    int2 b = base_of(xv.x, xv.y);
    atomicAdd(&cnt[b.x * NG + b.y], 1);
}

// ---- K2a: per-block (1024 cells) sums ----
__global__ __launch_bounds__(256)
void blocksum_kernel(const int* __restrict__ cnt, int* __restrict__ bsum) {
    __shared__ int sh[256];
    int t = threadIdx.x;
    int4 c = ((const int4*)cnt)[blockIdx.x * 256 + t];
    sh[t] = c.x + c.y + c.z + c.w;
    __syncthreads();
    for (int s = 128; s > 0; s >>= 1) {
        if (t < s) sh[t] += sh[t + s];
        __syncthreads();
    }
    if (t == 0) bsum[blockIdx.x] = sh[0];
}

// ---- K2b: exclusive scan of the 1024 block sums ----
__global__ __launch_bounds__(1024)
void scanb_kernel(const int* __restrict__ bsum, int* __restrict__ boff,
                  int* __restrict__ cell_start) {
    __shared__ int s[1024];
    int t = threadIdx.x;
    int v = bsum[t];
    s[t] = v;
    __syncthreads();
    for (int off = 1; off < 1024; off <<= 1) {
        int add = (t >= off) ? s[t - off] : 0;
        __syncthreads();
        s[t] += add;
        __syncthreads();
    }
    boff[t] = s[t] - v;
    if (t == 1023) cell_start[NCELL] = s[t];
}

// ---- K2c: per-block scan of 1024 counts + block offset -> cell_start, cursor ----
__global__ __launch_bounds__(256)
void scanc_kernel(const int* __restrict__ cnt, const int* __restrict__ boff,
                  int* __restrict__ cell_start, int* __restrict__ cursor) {
    __shared__ int tsum[256];
    int t = threadIdx.x;
    int gbase4 = blockIdx.x * 256 + t;
    int4 c = ((const int4*)cnt)[gbase4];
    int s1 = c.x, s2 = s1 + c.y, s3 = s2 + c.z, tot = s3 + c.w;
    tsum[t] = tot;
    __syncthreads();
    for (int off = 1; off < 256; off <<= 1) {
        int add = (t >= off) ? tsum[t - off] : 0;
        __syncthreads();
        tsum[t] += add;
        __syncthreads();
    }
    int excl = tsum[t] - tot;
    int g = boff[blockIdx.x] + excl;
    int4 outv = make_int4(g, g + s1, g + s2, g + s3);
    ((int4*)cell_start)[gbase4] = outv;
    ((int4*)cursor)[gbase4] = outv;
}

// ---- K3: per-particle physics, ALL coalesced; payload staged in d_out; 4B order scatter ----
__global__ __launch_bounds__(256)
void compute_scatter_kernel(const float* __restrict__ x, const float* __restrict__ v,
                            const float* __restrict__ Cin, const float* __restrict__ Fin,
                            const float* __restrict__ Jpin, const int* __restrict__ mat,
                            int* __restrict__ cursor, int* __restrict__ order,
                            float4* __restrict__ pay,
                            float* __restrict__ outF, float* __restrict__ outJp)
{
    int p = blockIdx.x * blockDim.x + threadIdx.x;
    if (p >= NPART) return;

    const float2 xv = ((const float2*)x)[p];
    const float2 vv = ((const float2*)v)[p];
    const float4 Cv = ((const float4*)Cin)[p];
    const float4 Fv = ((const float4*)Fin)[p];
    float xx = xv.x, xy = xv.y;
    float C00 = Cv.x, C01 = Cv.y, C10 = Cv.z, C11 = Cv.w;
    float F00 = Fv.x, F01 = Fv.y, F10 = Fv.z, F11 = Fv.w;

    // F = (I + DT*C) @ F
    float A00 = 1.0f + DT * C00, A01 = DT * C01, A10 = DT * C10, A11 = 1.0f + DT * C11;
    float G00 = A00 * F00 + A01 * F10;
    float G01 = A00 * F01 + A01 * F11;
    float G10 = A10 * F00 + A11 * F10;
    float G11 = A10 * F01 + A11 * F11;

    int m = mat[p];
    float Jp = Jpin[p];
    float h = fminf(fmaxf(expf(10.0f * (1.0f - Jp)), 0.1f), 5.0f);
    if (m == 1) h = 0.3f;
    float mu = (m == 0) ? 0.0f : MU0 * h;
    float la = LAM0 * h;

    // closed-form 2x2 SVD
    float Ee = 0.5f * (G00 + G11);
    float Hh = 0.5f * (G10 - G01);
    float Ff = 0.5f * (G00 - G11);
    float Gg = 0.5f * (G10 + G01);
    float Qq = sqrtf(Ee * Ee + Hh * Hh);
    float Rr = sqrtf(Ff * Ff + Gg * Gg);
    float s0 = Qq + Rr, s1 = Qq - Rr;
    float b1 = atan2f(Gg, Ff);
    float b2 = atan2f(Hh, Ee);
    float phi = 0.5f * (b1 + b2), th = 0.5f * (b1 - b2);
    float sphi, cphi, sth, cth;
    sincosf(phi, &sphi, &cphi);
    sincosf(th, &sth, &cth);

    float ns0 = s0, ns1 = s1;
    if (m == 2) {
        ns0 = fminf(fmaxf(s0, 1.0f - 2.5e-2f), 1.0f + 4.5e-3f);
        ns1 = fminf(fmaxf(s1, 1.0f - 2.5e-2f), 1.0f + 4.5e-3f);
        Jp = Jp * (s0 / ns0) * (s1 / ns1);
    }
    float J = ns0 * ns1;

    float FF00, FF01, FF10, FF11;
    if (m == 0) {
        float sj = sqrtf(J);
        FF00 = sj; FF01 = 0.0f; FF10 = 0.0f; FF11 = sj;
    } else if (m == 2) {
        FF00 = ns0 * cphi * cth + ns1 * sphi * sth;
        FF01 = ns0 * cphi * sth - ns1 * sphi * cth;
        FF10 = ns0 * sphi * cth - ns1 * cphi * sth;
        FF11 = ns0 * sphi * sth + ns1 * cphi * cth;
    } else {
        FF00 = G00; FF01 = G01; FF10 = G10; FF11 = G11;
    }

    // R = U V^T = rot(phi - th)
    float cr = cphi * cth + sphi * sth;
    float sr = sphi * cth - cphi * sth;

    float D00 = FF00 - cr,  D01 = FF01 + sr;
    float D10 = FF10 - sr,  D11 = FF11 - cr;
    float S00 = D00 * FF00 + D01 * FF01;
    float S01 = D00 * FF10 + D01 * FF11;
    float S10 = D10 * FF00 + D11 * FF01;
    float S11 = D10 * FF10 + D11 * FF11;
    float lj = la * J * (J - 1.0f);
    S00 = 2.0f * mu * S00 + lj;
    S01 = 2.0f * mu * S01;
    S10 = 2.0f * mu * S10;
    S11 = 2.0f * mu * S11 + lj;
    float a00 = STRESS_SCALE * S00 + P_MASS * C00;
    float a01 = STRESS_SCALE * S01 + P_MASS * C01;
    float a10 = STRESS_SCALE * S10 + P_MASS * C10;
    float a11 = STRESS_SCALE * S11 + P_MASS * C11;

    ((float4*)outF)[p] = make_float4(FF00, FF01, FF10, FF11);
    outJp[p] = Jp;

    // payload in PARTICLE order (coalesced, staged in d_out's x/v/C region)
    pay[2*p+0] = make_float4(xx, xy, P_MASS * vv.x, P_MASS * vv.y);
    pay[2*p+1] = make_float4(a00, a01, a10, a11);

    int2 b = base_of(xx, xy);
    int pos = atomicAdd(&cursor[b.x * NG + b.y], 1);
    order[pos] = p;
}

// ---- K4: reorder payload into cell-sorted order (random reads, coalesced writes) ----
__global__ __launch_bounds__(256)
void reorder_kernel(const float4* __restrict__ pay, const int* __restrict__ order,
                    float4* __restrict__ spay) {
    int t = blockIdx.x * blockDim.x + threadIdx.x;
    if (t >= NPART) return;
    int idx = order[t];
    float4 a = pay[2*idx+0];
    float4 b = pay[2*idx+1];
    spay[2*t+0] = a;
    spay[2*t+1] = b;
}

// ---- K5: atomic-free P2G gather over SORTED payload, fused grid update ----
__global__ __launch_bounds__(256)
void p2g_gather_grid_kernel(const float4* __restrict__ spay,
                            const int* __restrict__ cell_start,
                            const float* __restrict__ grav,
                            const float* __restrict__ astr,
                            const float* __restrict__ apos,
                            float* __restrict__ gv)
{
    int tile = blockIdx.x;                 // 0..4095
    int trow = threadIdx.x / CTILE;        // 0..15
    int tcol = threadIdx.x % CTILE;
    int cx = (tile / NBT) * CTILE + trow;  // this thread's cell
    int cy = (tile % NBT) * CTILE + tcol;

    float svx = 0.0f, svy = 0.0f, sm = 0.0f;
    int c0 = max(cy - 2, 0);

    #pragma unroll
    for (int d = 0; d < 3; ++d) {
        int gxp = cx - 2 + d;              // particle base row; i = 2-d
        if (gxp < 0 || gxp > NG - 1) continue;
        int row = gxp * NG;
        int s = cell_start[row + c0];
        int e = cell_start[row + cy + 1];
        const float io = (float)(2 - d);
        for (int t = s; t < e; ++t) {
            float4 p0 = spay[2*t+0];
            float4 p1 = spay[2*t+1];
            float fx = p0.x * INV_DX;
            float bxf = floorf(fx - 0.5f);
            float fxx = fx - bxf;
            float fy = p0.y * INV_DX;
            float byf = floorf(fy - 0.5f);
            float fxy = fy - byf;
            int j = cy - (int)byf;
            if (j < 0 || j > 2) continue;  // defensive (empty in practice)
            float wx;
            if (d == 0)      wx = 0.5f * (fxx - 0.5f) * (fxx - 0.5f);        // i=2
            else if (d == 1) wx = 0.75f - (fxx - 1.0f) * (fxx - 1.0f);       // i=1
            else             wx = 0.5f * (1.5f - fxx) * (1.5f - fxx);        // i=0
            float w0 = 0.5f * (1.5f - fxy) * (1.5f - fxy);
            float w1 = 0.75f - (fxy - 1.0f) * (fxy - 1.0f);
            float w2 = 0.5f * (fxy - 0.5f) * (fxy - 0.5f);
            float wy = (j == 0) ? w0 : ((j == 1) ? w1 : w2);
            float wgt = wx * wy;
            float dpx = (io - fxx) * DX;
            float dpy = ((float)j - fxy) * DX;
            svx += wgt * (p0.z + p1.x * dpx + p1.y * dpy);
            svy += wgt * (p0.w + p1.z * dpx + p1.w * dpy);
            sm  += wgt * P_MASS;
        }
    }

    // fused grid update
    float vx = 0.0f, vy = 0.0f;
    if (sm > 0.0f) {
        vx = svx / sm + GRAV_SCALE * grav[0];
        vy = svy / sm + GRAV_SCALE * grav[1];
        float dxp = apos[0] - DX * (float)cx;
        float dyp = apos[1] - DX * (float)cy;
        float nrm = sqrtf(dxp * dxp + dyp * dyp);
        float k = astr[0] * ATTR_SCALE / (0.01f + nrm);
        vx += dxp * k;
        vy += dyp * k;
        if (cx < 3 && vx < 0.0f) vx = 0.0f;
        if (cx > NG - 3 && vx > 0.0f) vx = 0.0f;
        if (cy < 3 && vy < 0.0f) vy = 0.0f;
        if (cy > NG - 3 && vy > 0.0f) vy = 0.0f;
    }
    ((float2*)gv)[cx * NG + cy] = make_float2(vx, vy);
}

// ---- K6: G2P (overwrites the staging region with real outputs) ----
__global__ __launch_bounds__(256)
void g2p_kernel(const float* __restrict__ x, const float* __restrict__ gv,
                float* __restrict__ outX, float* __restrict__ outV,
                float* __restrict__ outC)
{
    int p = blockIdx.x * blockDim.x + threadIdx.x;
    if (p >= NPART) return;

    const float2 xv = ((const float2*)x)[p];
    float xx = xv.x, xy = xv.y;
    float bxf = floorf(xx * INV_DX - 0.5f);
    float byf = floorf(xy * INV_DX - 0.5f);
    int bx = (int)bxf, by = (int)byf;
    float fxx = xx * INV_DX - bxf;
    float fxy = xy * INV_DX - byf;

    float wxs[3], wys[3];
    wxs[0] = 0.5f * (1.5f - fxx) * (1.5f - fxx);
    wxs[1] = 0.75f - (fxx - 1.0f) * (fxx - 1.0f);
    wxs[2] = 0.5f * (fxx - 0.5f) * (fxx - 0.5f);
    wys[0] = 0.5f * (1.5f - fxy) * (1.5f - fxy);
    wys[1] = 0.75f - (fxy - 1.0f) * (fxy - 1.0f);
    wys[2] = 0.5f * (fxy - 0.5f) * (fxy - 0.5f);

    float nvx = 0.0f, nvy = 0.0f;
    float c00 = 0.0f, c01 = 0.0f, c10 = 0.0f, c11 = 0.0f;

    #pragma unroll
    for (int i = 0; i < 3; ++i) {
        int gi = min(max(bx + i, 0), NG - 1);
        float dpx = (float)i - fxx;
        #pragma unroll
        for (int j = 0; j < 3; ++j) {
            int gj = min(max(by + j, 0), NG - 1);
            float dpy = (float)j - fxy;
            int idx = gi * NG + gj;
            float wgt = wxs[i] * wys[j];
            float2 g = ((const float2*)gv)[idx];
            nvx += wgt * g.x;
            nvy += wgt * g.y;
            c00 += wgt * g.x * dpx;
            c01 += wgt * g.x * dpy;
            c10 += wgt * g.y * dpx;
            c11 += wgt * g.y * dpy;
        }
    }
    float cs = 4.0f * INV_DX;
    ((float2*)outV)[p] = make_float2(nvx, nvy);
    ((float2*)outX)[p] = make_float2(xx + DT * nvx, xy + DT * nvy);
    ((float4*)outC)[p] = make_float4(cs * c00, cs * c01, cs * c10, cs * c11);
}

extern "C" void kernel_launch(void* const* d_in, const int* in_sizes, int n_in,
                              void* d_out, int out_size, void* d_ws, size_t ws_size,
                              hipStream_t stream)
{
    const float* x    = (const float*)d_in[0];
    const float* v    = (const float*)d_in[1];
    const float* C    = (const float*)d_in[2];
    const float* F    = (const float*)d_in[3];
    const float* Jp   = (const float*)d_in[4];
    const float* grav = (const float*)d_in[5];
    const float* astr = (const float*)d_in[6];
    const float* apos = (const float*)d_in[7];
    const int*   mat  = (const int*)d_in[8];

    float* out   = (float*)d_out;
    float* outX  = out;
    float* outV  = out + 2 * NPART;
    float* outC  = out + 4 * NPART;
    float* outF  = out + 8 * NPART;
    float* outJp = out + 12 * NPART;

    // pay staged in d_out[0 .. 8*NPART): dead until g2p overwrites it (after
    // reorder has consumed it). outF/outJp live outside this region.
    float4* pay  = (float4*)out;                  // 2*NPART float4 (37 MB)

    // workspace layout (4B units). gv aliases cnt+cursor (disjoint lifetimes):
    //   [0, NCELL)            : cnt    (K1..K2c)  | gv low half  (K5..K6)
    //   [NCELL, 2*NCELL)      : cursor (K2c..K3)  | gv high half (K5..K6)
    //   [2*NCELL, 3*NCELL+1]  : cell_start
    //   then bsum[1024], boff[1024], order[NPART], pad, spay[2*NPART] float4
    int*   ws_i      = (int*)d_ws;
    int*   cnt       = ws_i;
    int*   cursor    = ws_i + NCELL;
    float* gv        = (float*)d_ws;              // 2*NCELL floats
    int*   cell_start= ws_i + 2 * NCELL;          // NCELL+1
    int*   bsum      = cell_start + NCELL + 1;    // 1024
    int*   boff      = bsum + 1024;               // 1024
    int*   order     = boff + 1024;               // NPART
    size_t spay_off  = (size_t)(3 * NCELL + 3 * 1024 + NPART + 16);
    spay_off = (spay_off + 3) & ~(size_t)3;       // 16B-align (float4 units)
    float4* spay     = (float4*)(ws_i + spay_off);// 2*NPART float4 (37 MB)

    const int TB = 256;
    hipMemsetAsync(cnt, 0, (size_t)NCELL * sizeof(int), stream);
    count_kernel   <<<(NPART + TB - 1) / TB, TB, 0, stream>>>(x, cnt);
    blocksum_kernel<<<NCELL / 1024, TB, 0, stream>>>(cnt, bsum);
    scanb_kernel   <<<1, 1024, 0, stream>>>(bsum, boff, cell_start);
    scanc_kernel   <<<NCELL / 1024, TB, 0, stream>>>(cnt, boff, cell_start, cursor);
    compute_scatter_kernel<<<(NPART + TB - 1) / TB, TB, 0, stream>>>(
        x, v, C, F, Jp, mat, cursor, order, pay, outF, outJp);
    reorder_kernel <<<(NPART + TB - 1) / TB, TB, 0, stream>>>(pay, order, spay);
    p2g_gather_grid_kernel<<<NBT * NBT, TB, 0, stream>>>(
        spay, cell_start, grav, astr, apos, gv);
    g2p_kernel     <<<(NPART + TB - 1) / TB, TB, 0, stream>>>(x, gv, outX, outV, outC);
}

// Round 9
// 225.195 us; speedup vs baseline: 1.3547x; 1.1187x over previous
//
#include <hip/hip_runtime.h>
#include <math.h>

namespace {
constexpr int   QUALITY = 8;
constexpr int   NPART   = 18000 * QUALITY * QUALITY;  // 1,152,000
constexpr int   NG      = 128 * QUALITY;              // 1024
constexpr int   NCELL   = NG * NG;                    // 1,048,576
constexpr int   CTILE   = 16;                         // gather tile side (cells)
constexpr int   NBT     = NG / CTILE;                 // 64 tiles per side
constexpr float DX      = 1.0f / (float)NG;
constexpr float INV_DX  = (float)NG;
constexpr float DT      = (float)(1e-4 / (double)QUALITY);
constexpr float P_VOL   = (float)((0.5 / (double)NG) * (0.5 / (double)NG));
constexpr float P_MASS  = P_VOL;  // density 1.0
constexpr float MU0     = (float)(5000.0 / (2.0 * (1.0 + 0.2)));
constexpr float LAM0    = (float)(5000.0 * 0.2 / ((1.0 + 0.2) * (1.0 - 0.4)));
constexpr float STRESS_SCALE = (float)(-(1e-4 / 8.0) * ((0.5 / 1024.0) * (0.5 / 1024.0)) * 4.0 * 1024.0 * 1024.0);
constexpr float GRAV_SCALE   = (float)((1e-4 / 8.0) * 30.0);
constexpr float ATTR_SCALE   = (float)((1e-4 / 8.0) * 100.0);

// base cell of a particle, clamped so base+2 is in range (matches ref for this data)
__device__ __forceinline__ int2 base_of(float xx, float xy) {
    int bx = (int)floorf(xx * INV_DX - 0.5f);
    int by = (int)floorf(xy * INV_DX - 0.5f);
    bx = min(max(bx, 0), NG - 3);
    by = min(max(by, 0), NG - 3);
    return make_int2(bx, by);
}
}

// ---- K1: per-particle physics (all coalesced) + histogram atomic ----
__global__ __launch_bounds__(256)
void physics_kernel(const float* __restrict__ x, const float* __restrict__ v,
                    const float* __restrict__ Cin, const float* __restrict__ Fin,
                    const float* __restrict__ Jpin, const int* __restrict__ mat,
                    int* __restrict__ cnt, float4* __restrict__ pay,
                    float* __restrict__ outF, float* __restrict__ outJp)
{
    int p = blockIdx.x * blockDim.x + threadIdx.x;
    if (p >= NPART) return;

    const float2 xv = ((const float2*)x)[p];
    const float2 vv = ((const float2*)v)[p];
    const float4 Cv = ((const float4*)Cin)[p];
    const float4 Fv = ((const float4*)Fin)[p];
    float xx = xv.x, xy = xv.y;
    float C00 = Cv.x, C01 = Cv.y, C10 = Cv.z, C11 = Cv.w;
    float F00 = Fv.x, F01 = Fv.y, F10 = Fv.z, F11 = Fv.w;

    // F = (I + DT*C) @ F
    float A00 = 1.0f + DT * C00, A01 = DT * C01, A10 = DT * C10, A11 = 1.0f + DT * C11;
    float G00 = A00 * F00 + A01 * F10;
    float G01 = A00 * F01 + A01 * F11;
    float G10 = A10 * F00 + A11 * F10;
    float G11 = A10 * F01 + A11 * F11;

    int m = mat[p];
    float Jp = Jpin[p];
    float h = fminf(fmaxf(expf(10.0f * (1.0f - Jp)), 0.1f), 5.0f);
    if (m == 1) h = 0.3f;
    float mu = (m == 0) ? 0.0f : MU0 * h;
    float la = LAM0 * h;

    // closed-form 2x2 SVD
    float Ee = 0.5f * (G00 + G11);
    float Hh = 0.5f * (G10 - G01);
    float Ff = 0.5f * (G00 - G11);
    float Gg = 0.5f * (G10 + G01);
    float Qq = sqrtf(Ee * Ee + Hh * Hh);
    float Rr = sqrtf(Ff * Ff + Gg * Gg);
    float s0 = Qq + Rr, s1 = Qq - Rr;
    float b1 = atan2f(Gg, Ff);
    float b2 = atan2f(Hh, Ee);
    float phi = 0.5f * (b1 + b2), th = 0.5f * (b1 - b2);
    float sphi, cphi, sth, cth;
    sincosf(phi, &sphi, &cphi);
    sincosf(th, &sth, &cth);

    float ns0 = s0, ns1 = s1;
    if (m == 2) {
        ns0 = fminf(fmaxf(s0, 1.0f - 2.5e-2f), 1.0f + 4.5e-3f);
        ns1 = fminf(fmaxf(s1, 1.0f - 2.5e-2f), 1.0f + 4.5e-3f);
        Jp = Jp * (s0 / ns0) * (s1 / ns1);
    }
    float J = ns0 * ns1;

    float FF00, FF01, FF10, FF11;
    if (m == 0) {
        float sj = sqrtf(J);
        FF00 = sj; FF01 = 0.0f; FF10 = 0.0f; FF11 = sj;
    } else if (m == 2) {
        FF00 = ns0 * cphi * cth + ns1 * sphi * sth;
        FF01 = ns0 * cphi * sth - ns1 * sphi * cth;
        FF10 = ns0 * sphi * cth - ns1 * cphi * sth;
        FF11 = ns0 * sphi * sth + ns1 * cphi * cth;
    } else {
        FF00 = G00; FF01 = G01; FF10 = G10; FF11 = G11;
    }

    // R = U V^T = rot(phi - th)
    float cr = cphi * cth + sphi * sth;
    float sr = sphi * cth - cphi * sth;

    float D00 = FF00 - cr,  D01 = FF01 + sr;
    float D10 = FF10 - sr,  D11 = FF11 - cr;
    float S00 = D00 * FF00 + D01 * FF01;
    float S01 = D00 * FF10 + D01 * FF11;
    float S10 = D10 * FF00 + D11 * FF01;
    float S11 = D10 * FF10 + D11 * FF11;
    float lj = la * J * (J - 1.0f);
    S00 = 2.0f * mu * S00 + lj;
    S01 = 2.0f * mu * S01;
    S10 = 2.0f * mu * S10;
    S11 = 2.0f * mu * S11 + lj;
    float a00 = STRESS_SCALE * S00 + P_MASS * C00;
    float a01 = STRESS_SCALE * S01 + P_MASS * C01;
    float a10 = STRESS_SCALE * S10 + P_MASS * C10;
    float a11 = STRESS_SCALE * S11 + P_MASS * C11;

    ((float4*)outF)[p] = make_float4(FF00, FF01, FF10, FF11);
    outJp[p] = Jp;

    // payload in PARTICLE order (coalesced, staged in d_out's x/v/C region)
    pay[2*p+0] = make_float4(xx, xy, P_MASS * vv.x, P_MASS * vv.y);
    pay[2*p+1] = make_float4(a00, a01, a10, a11);

    // histogram
    int2 b = base_of(xx, xy);
    atomicAdd(&cnt[b.x * NG + b.y], 1);
}

// ---- K2a: per-block (1024 cells) sums ----
__global__ __launch_bounds__(256)
void blocksum_kernel(const int* __restrict__ cnt, int* __restrict__ bsum) {
    __shared__ int sh[256];
    int t = threadIdx.x;
    int4 c = ((const int4*)cnt)[blockIdx.x * 256 + t];
    sh[t] = c.x + c.y + c.z + c.w;
    __syncthreads();
    for (int s = 128; s > 0; s >>= 1) {
        if (t < s) sh[t] += sh[t + s];
        __syncthreads();
    }
    if (t == 0) bsum[blockIdx.x] = sh[0];
}

// ---- K2b: exclusive scan of the 1024 block sums ----
__global__ __launch_bounds__(1024)
void scanb_kernel(const int* __restrict__ bsum, int* __restrict__ boff,
                  int* __restrict__ cell_start) {
    __shared__ int s[1024];
    int t = threadIdx.x;
    int v = bsum[t];
    s[t] = v;
    __syncthreads();
    for (int off = 1; off < 1024; off <<= 1) {
        int add = (t >= off) ? s[t - off] : 0;
        __syncthreads();
        s[t] += add;
        __syncthreads();
    }
    boff[t] = s[t] - v;
    if (t == 1023) cell_start[NCELL] = s[t];
}

// ---- K2c: per-block scan of 1024 counts + block offset -> cell_start, cursor ----
__global__ __launch_bounds__(256)
void scanc_kernel(const int* __restrict__ cnt, const int* __restrict__ boff,
                  int* __restrict__ cell_start, int* __restrict__ cursor) {
    __shared__ int tsum[256];
    int t = threadIdx.x;
    int gbase4 = blockIdx.x * 256 + t;
    int4 c = ((const int4*)cnt)[gbase4];
    int s1 = c.x, s2 = s1 + c.y, s3 = s2 + c.z, tot = s3 + c.w;
    tsum[t] = tot;
    __syncthreads();
    for (int off = 1; off < 256; off <<= 1) {
        int add = (t >= off) ? tsum[t - off] : 0;
        __syncthreads();
        tsum[t] += add;
        __syncthreads();
    }
    int excl = tsum[t] - tot;
    int g = boff[blockIdx.x] + excl;
    int4 outv = make_int4(g, g + s1, g + s2, g + s3);
    ((int4*)cell_start)[gbase4] = outv;
    ((int4*)cursor)[gbase4] = outv;
}

// ---- K3: scatter payload to cell-sorted position (coalesced read, 32B scattered write) ----
__global__ __launch_bounds__(256)
void scatter_kernel(const float4* __restrict__ pay, int* __restrict__ cursor,
                    float4* __restrict__ spay)
{
    int p = blockIdx.x * blockDim.x + threadIdx.x;
    if (p >= NPART) return;
    float4 q0 = pay[2*p+0];
    float4 q1 = pay[2*p+1];
    int2 b = base_of(q0.x, q0.y);
    int pos = atomicAdd(&cursor[b.x * NG + b.y], 1);
    spay[2*pos+0] = q0;
    spay[2*pos+1] = q1;
}

// ---- K4: atomic-free P2G gather over SORTED payload, fused grid update ----
__global__ __launch_bounds__(256)
void p2g_gather_grid_kernel(const float4* __restrict__ spay,
                            const int* __restrict__ cell_start,
                            const float* __restrict__ grav,
                            const float* __restrict__ astr,
                            const float* __restrict__ apos,
                            float* __restrict__ gv)
{
    int tile = blockIdx.x;                 // 0..4095
    int trow = threadIdx.x / CTILE;        // 0..15
    int tcol = threadIdx.x % CTILE;
    int cx = (tile / NBT) * CTILE + trow;  // this thread's cell
    int cy = (tile % NBT) * CTILE + tcol;

    float svx = 0.0f, svy = 0.0f, sm = 0.0f;
    int c0 = max(cy - 2, 0);

    #pragma unroll
    for (int d = 0; d < 3; ++d) {
        int gxp = cx - 2 + d;              // particle base row; i = 2-d
        if (gxp < 0 || gxp > NG - 1) continue;
        int row = gxp * NG;
        int s = cell_start[row + c0];
        int e = cell_start[row + cy + 1];
        const float io = (float)(2 - d);
        for (int t = s; t < e; ++t) {
            float4 p0 = spay[2*t+0];
            float4 p1 = spay[2*t+1];
            float fx = p0.x * INV_DX;
            float bxf = floorf(fx - 0.5f);
            float fxx = fx - bxf;
            float fy = p0.y * INV_DX;
            float byf = floorf(fy - 0.5f);
            float fxy = fy - byf;
            int j = cy - (int)byf;
            if (j < 0 || j > 2) continue;  // defensive (empty in practice)
            float wx;
            if (d == 0)      wx = 0.5f * (fxx - 0.5f) * (fxx - 0.5f);        // i=2
            else if (d == 1) wx = 0.75f - (fxx - 1.0f) * (fxx - 1.0f);       // i=1
            else             wx = 0.5f * (1.5f - fxx) * (1.5f - fxx);        // i=0
            float w0 = 0.5f * (1.5f - fxy) * (1.5f - fxy);
            float w1 = 0.75f - (fxy - 1.0f) * (fxy - 1.0f);
            float w2 = 0.5f * (fxy - 0.5f) * (fxy - 0.5f);
            float wy = (j == 0) ? w0 : ((j == 1) ? w1 : w2);
            float wgt = wx * wy;
            float dpx = (io - fxx) * DX;
            float dpy = ((float)j - fxy) * DX;
            svx += wgt * (p0.z + p1.x * dpx + p1.y * dpy);
            svy += wgt * (p0.w + p1.z * dpx + p1.w * dpy);
            sm  += wgt * P_MASS;
        }
    }

    // fused grid update
    float vx = 0.0f, vy = 0.0f;
    if (sm > 0.0f) {
        vx = svx / sm + GRAV_SCALE * grav[0];
        vy = svy / sm + GRAV_SCALE * grav[1];
        float dxp = apos[0] - DX * (float)cx;
        float dyp = apos[1] - DX * (float)cy;
        float nrm = sqrtf(dxp * dxp + dyp * dyp);
        float k = astr[0] * ATTR_SCALE / (0.01f + nrm);
        vx += dxp * k;
        vy += dyp * k;
        if (cx < 3 && vx < 0.0f) vx = 0.0f;
        if (cx > NG - 3 && vx > 0.0f) vx = 0.0f;
        if (cy < 3 && vy < 0.0f) vy = 0.0f;
        if (cy > NG - 3 && vy > 0.0f) vy = 0.0f;
    }
    ((float2*)gv)[cx * NG + cy] = make_float2(vx, vy);
}

// ---- K5: G2P (overwrites the d_out staging region with real outputs) ----
__global__ __launch_bounds__(256)
void g2p_kernel(const float* __restrict__ x, const float* __restrict__ gv,
                float* __restrict__ outX, float* __restrict__ outV,
                float* __restrict__ outC)
{
    int p = blockIdx.x * blockDim.x + threadIdx.x;
    if (p >= NPART) return;

    const float2 xv = ((const float2*)x)[p];
    float xx = xv.x, xy = xv.y;
    float bxf = floorf(xx * INV_DX - 0.5f);
    float byf = floorf(xy * INV_DX - 0.5f);
    int bx = (int)bxf, by = (int)byf;
    float fxx = xx * INV_DX - bxf;
    float fxy = xy * INV_DX - byf;

    float wxs[3], wys[3];
    wxs[0] = 0.5f * (1.5f - fxx) * (1.5f - fxx);
    wxs[1] = 0.75f - (fxx - 1.0f) * (fxx - 1.0f);
    wxs[2] = 0.5f * (fxx - 0.5f) * (fxx - 0.5f);
    wys[0] = 0.5f * (1.5f - fxy) * (1.5f - fxy);
    wys[1] = 0.75f - (fxy - 1.0f) * (fxy - 1.0f);
    wys[2] = 0.5f * (fxy - 0.5f) * (fxy - 0.5f);

    float nvx = 0.0f, nvy = 0.0f;
    float c00 = 0.0f, c01 = 0.0f, c10 = 0.0f, c11 = 0.0f;

    #pragma unroll
    for (int i = 0; i < 3; ++i) {
        int gi = min(max(bx + i, 0), NG - 1);
        float dpx = (float)i - fxx;
        #pragma unroll
        for (int j = 0; j < 3; ++j) {
            int gj = min(max(by + j, 0), NG - 1);
            float dpy = (float)j - fxy;
            int idx = gi * NG + gj;
            float wgt = wxs[i] * wys[j];
            float2 g = ((const float2*)gv)[idx];
            nvx += wgt * g.x;
            nvy += wgt * g.y;
            c00 += wgt * g.x * dpx;
            c01 += wgt * g.x * dpy;
            c10 += wgt * g.y * dpx;
            c11 += wgt * g.y * dpy;
        }
    }
    float cs = 4.0f * INV_DX;
    ((float2*)outV)[p] = make_float2(nvx, nvy);
    ((float2*)outX)[p] = make_float2(xx + DT * nvx, xy + DT * nvy);
    ((float4*)outC)[p] = make_float4(cs * c00, cs * c01, cs * c10, cs * c11);
}

extern "C" void kernel_launch(void* const* d_in, const int* in_sizes, int n_in,
                              void* d_out, int out_size, void* d_ws, size_t ws_size,
                              hipStream_t stream)
{
    const float* x    = (const float*)d_in[0];
    const float* v    = (const float*)d_in[1];
    const float* C    = (const float*)d_in[2];
    const float* F    = (const float*)d_in[3];
    const float* Jp   = (const float*)d_in[4];
    const float* grav = (const float*)d_in[5];
    const float* astr = (const float*)d_in[6];
    const float* apos = (const float*)d_in[7];
    const int*   mat  = (const int*)d_in[8];

    float* out   = (float*)d_out;
    float* outX  = out;
    float* outV  = out + 2 * NPART;
    float* outC  = out + 4 * NPART;
    float* outF  = out + 8 * NPART;
    float* outJp = out + 12 * NPART;

    // pay staged in d_out[0 .. 8*NPART): dead until g2p overwrites it (after
    // scatter has consumed it). outF/outJp live outside this region.
    float4* pay  = (float4*)out;                  // 2*NPART float4 (37 MB)

    // workspace layout (4B units). gv aliases cnt+cursor (disjoint lifetimes):
    //   [0, NCELL)            : cnt    (K1..K2c)  | gv low half  (K4..K5)
    //   [NCELL, 2*NCELL)      : cursor (K2c..K3)  | gv high half (K4..K5)
    //   [2*NCELL, 3*NCELL+1]  : cell_start
    //   then bsum[1024], boff[1024], pad, spay[2*NPART] float4
    int*   ws_i      = (int*)d_ws;
    int*   cnt       = ws_i;
    int*   cursor    = ws_i + NCELL;
    float* gv        = (float*)d_ws;              // 2*NCELL floats
    int*   cell_start= ws_i + 2 * NCELL;          // NCELL+1
    int*   bsum      = cell_start + NCELL + 1;    // 1024
    int*   boff      = bsum + 1024;               // 1024
    size_t spay_off  = (size_t)(3 * NCELL + 2 * 1024 + 16);
    spay_off = (spay_off + 3) & ~(size_t)3;       // 16B-align (float4 units)
    float4* spay     = (float4*)(ws_i + spay_off);// 2*NPART float4 (37 MB)

    const int TB = 256;
    hipMemsetAsync(cnt, 0, (size_t)NCELL * sizeof(int), stream);
    physics_kernel<<<(NPART + TB - 1) / TB, TB, 0, stream>>>(
        x, v, C, F, Jp, mat, cnt, pay, outF, outJp);
    blocksum_kernel<<<NCELL / 1024, TB, 0, stream>>>(cnt, bsum);
    scanb_kernel   <<<1, 1024, 0, stream>>>(bsum, boff, cell_start);
    scanc_kernel   <<<NCELL / 1024, TB, 0, stream>>>(cnt, boff, cell_start, cursor);
    scatter_kernel <<<(NPART + TB - 1) / TB, TB, 0, stream>>>(pay, cursor, spay);
    p2g_gather_grid_kernel<<<NBT * NBT, TB, 0, stream>>>(
        spay, cell_start, grav, astr, apos, gv);
    g2p_kernel     <<<(NPART + TB - 1) / TB, TB, 0, stream>>>(x, gv, outX, outV, outC);
}